// Round 1
// baseline (1067.355 us; speedup 1.0000x reference)
//
#include <hip/hip_runtime.h>
#include <hip/hip_bf16.h>

// ---------- types ----------
typedef __bf16 bf16x8 __attribute__((ext_vector_type(8)));
typedef float  f32x4  __attribute__((ext_vector_type(4)));

#define H_DIM 112
#define W_DIM 112
#define CIN 64
#define CMID 192          // 3*64
#define COUT 128
#define NB 16

// ---------------------------------------------------------------
// Kernel A: repack weights [co][ci][kh][kw] fp32 -> [khw][co][ci] bf16
// ---------------------------------------------------------------
__global__ __launch_bounds__(256) void repack_w_kernel(
    const float* __restrict__ w, __hip_bfloat16* __restrict__ wr)
{
    int idx = blockIdx.x * 256 + threadIdx.x;
    if (idx < 9 * COUT * CMID) {
        int ci  = idx % CMID;
        int t   = idx / CMID;
        int co  = t % COUT;
        int khw = t / COUT;
        wr[idx] = __float2bfloat16(w[(co * CMID + ci) * 9 + khw]);
    }
}

// ---------------------------------------------------------------
// Kernel B: bilinear shift + Maclaurin powers -> y NHWC bf16
// y layout: [n][h][w][c3], c3 = c + 64*(power-1), shape (16,112,112,192)
// one block per (n,h); LDS transpose for coalesced NHWC writes
// ---------------------------------------------------------------
#define TSTRIDE 196   // 192 + 4 pad (98 dwords => stride 2 mod 32 banks)

__global__ __launch_bounds__(256) void shift_pow_kernel(
    const float* __restrict__ x, const float* __restrict__ shifts,
    __hip_bfloat16* __restrict__ y)
{
    __shared__ __hip_bfloat16 tile[W_DIM * TSTRIDE];

    const int n   = blockIdx.y;
    const int h   = blockIdx.x;
    const int tid = threadIdx.x;
    const int wl  = tid & 63;
    const int c0  = tid >> 6;   // 0..3

    for (int c = c0; c < CIN; c += 4) {
        float sx = shifts[2 * c]     * 4.0f;
        float sy = shifts[2 * c + 1] * 4.0f;
        float fx = floorf(sx), fy = floorf(sy);
        float wx = sx - fx,    wy = sy - fy;
        int   ix = (int)fx,    iy = (int)fy;

        int r0 = h + iy, r1 = r0 + 1;
        bool r0v = (unsigned)r0 < (unsigned)H_DIM;
        bool r1v = (unsigned)r1 < (unsigned)H_DIM;

        const float* xp  = x + ((size_t)(n * CIN + c) * H_DIM) * W_DIM;
        const float* xr0 = xp + r0 * W_DIM;
        const float* xr1 = xp + r1 * W_DIM;

        #pragma unroll
        for (int wb = 0; wb < 2; ++wb) {
            int px = wb * 64 + wl;
            if (px < W_DIM) {
                int cl0 = px + ix, cl1 = cl0 + 1;
                bool c0v = (unsigned)cl0 < (unsigned)W_DIM;
                bool c1v = (unsigned)cl1 < (unsigned)W_DIM;
                float t00 = (r0v && c0v) ? xr0[cl0] : 0.0f;
                float t01 = (r0v && c1v) ? xr0[cl1] : 0.0f;
                float t10 = (r1v && c0v) ? xr1[cl0] : 0.0f;
                float t11 = (r1v && c1v) ? xr1[cl1] : 0.0f;
                float v  = (1.0f - wy) * ((1.0f - wx) * t00 + wx * t01)
                         +         wy  * ((1.0f - wx) * t10 + wx * t11);
                float v2 = v * v;
                float v3 = v2 * v;
                __hip_bfloat16* tp = &tile[px * TSTRIDE];
                tp[c]       = __float2bfloat16(v);
                tp[c + 64]  = __float2bfloat16(v2);
                tp[c + 128] = __float2bfloat16(v3);
            }
        }
    }
    __syncthreads();

    // coalesced write-out: 112 px * 96 dwords = 10752 dwords, 42 iters * 256 thr
    const unsigned* tl = (const unsigned*)tile;
    unsigned* yo = (unsigned*)(y + ((size_t)(n * H_DIM + h) * W_DIM) * CMID);
    #pragma unroll 2
    for (int it = 0; it < 42; ++it) {
        int idx = it * 256 + tid;
        int px  = idx / 96;
        int cp  = idx - px * 96;
        yo[idx] = tl[px * 98 + cp];
    }
}

// ---------------------------------------------------------------
// Kernel C: implicit-GEMM 3x3 conv, bf16 MFMA 16x16x32
// block: 64 co x 64 px (one output row segment); 4 waves = 4 co-subtiles
// A (weights): [khw][co][ci] bf16 ; B (im2col y): NHWC bf16 (direct global)
// ---------------------------------------------------------------
__global__ __launch_bounds__(256) void conv_kernel(
    const __bf16* __restrict__ y,    // [16][112][112][192]
    const __bf16* __restrict__ wr,   // [9][128][192]
    const float* __restrict__ bias,
    float* __restrict__ out)         // [16][128][112][112]
{
    const int tid  = threadIdx.x;
    const int lane = tid & 63;
    const int wid  = tid >> 6;     // 0..3
    const int m    = lane & 15;    // A: co_local ; B: px_local ; D: col
    const int quad = lane >> 4;    // k-group ; D: row-group

    const int h       = blockIdx.x >> 1;
    const int wt      = blockIdx.x & 1;
    const int co_base = blockIdx.y * 64 + wid * 16;
    const int n       = blockIdx.z;
    const int j0      = wt * 64;
    const int npt     = wt ? 3 : 4;   // 112 = 64 + 48

    f32x4 acc[4];
    #pragma unroll
    for (int p = 0; p < 4; ++p)
        #pragma unroll
        for (int r = 0; r < 4; ++r) acc[p][r] = 0.0f;

    bf16x8 zero8;
    #pragma unroll
    for (int i = 0; i < 8; ++i) zero8[i] = (__bf16)0.0f;

    const __bf16* ybase = y + (size_t)n * (H_DIM * W_DIM * CMID);

    for (int kh = 0; kh < 3; ++kh) {
        int row = h + kh - 1;
        bool rv = (unsigned)row < (unsigned)H_DIM;
        const __bf16* yrow = ybase + (size_t)row * (W_DIM * CMID);
        for (int chunk = 0; chunk < 6; ++chunk) {
            int kb = chunk * 32 + quad * 8;
            #pragma unroll
            for (int kw = 0; kw < 3; ++kw) {
                bf16x8 afrag = *(const bf16x8*)(
                    wr + (size_t)((kh * 3 + kw) * COUT + co_base + m) * CMID + kb);
                #pragma unroll
                for (int pt = 0; pt < 4; ++pt) {
                    if (pt < npt) {
                        int j = j0 + pt * 16 + m + kw - 1;
                        bf16x8 bfrag;
                        if (rv && (unsigned)j < (unsigned)W_DIM)
                            bfrag = *(const bf16x8*)(yrow + (size_t)j * CMID + kb);
                        else
                            bfrag = zero8;
                        acc[pt] = __builtin_amdgcn_mfma_f32_16x16x32_bf16(
                            afrag, bfrag, acc[pt], 0, 0, 0);
                    }
                }
            }
        }
    }

    // epilogue: D col = px (lane&15) -> coalesced stores; row = quad*4+r -> co
    float bvals[4];
    #pragma unroll
    for (int r = 0; r < 4; ++r) bvals[r] = bias[co_base + quad * 4 + r];

    #pragma unroll
    for (int pt = 0; pt < 4; ++pt) {
        int j = j0 + pt * 16 + m;
        if (j < W_DIM) {
            #pragma unroll
            for (int r = 0; r < 4; ++r) {
                int co = co_base + quad * 4 + r;
                out[(((size_t)n * COUT + co) * H_DIM + h) * W_DIM + j] =
                    acc[pt][r] + bvals[r];
            }
        }
    }
}

// ---------------------------------------------------------------
extern "C" void kernel_launch(void* const* d_in, const int* in_sizes, int n_in,
                              void* d_out, int out_size, void* d_ws, size_t ws_size,
                              hipStream_t stream) {
    const float* x      = (const float*)d_in[0];
    const float* w      = (const float*)d_in[1];
    const float* bias   = (const float*)d_in[2];
    const float* shifts = (const float*)d_in[3];
    float* out = (float*)d_out;

    // workspace layout: y (NHWC bf16) then repacked weights
    __hip_bfloat16* y  = (__hip_bfloat16*)d_ws;                       // 77,070,336 B
    __hip_bfloat16* wr = (__hip_bfloat16*)((char*)d_ws + 77070336);   //    442,368 B

    repack_w_kernel<<<dim3((9 * COUT * CMID + 255) / 256), 256, 0, stream>>>(w, wr);
    shift_pow_kernel<<<dim3(H_DIM, NB), 256, 0, stream>>>(x, shifts, y);
    conv_kernel<<<dim3(H_DIM * 2, 2, NB), 256, 0, stream>>>(
        (const __bf16*)y, (const __bf16*)wr, bias, out);
}

// Round 2
// 357.265 us; speedup vs baseline: 2.9876x; 2.9876x over previous
//
#include <hip/hip_runtime.h>
#include <hip/hip_bf16.h>

// ---------- types ----------
typedef __bf16 bf16x8 __attribute__((ext_vector_type(8)));
typedef float  f32x4  __attribute__((ext_vector_type(4)));

#define H_DIM 112
#define W_DIM 112
#define CIN 64
#define CMID 192          // 3*64
#define COUT 128
#define NB 16

// ---------------------------------------------------------------
// Kernel A: repack weights [co][ci][kh][kw] fp32 -> [khw][co][ci] bf16
// ---------------------------------------------------------------
__global__ __launch_bounds__(256) void repack_w_kernel(
    const float* __restrict__ w, __hip_bfloat16* __restrict__ wr)
{
    int idx = blockIdx.x * 256 + threadIdx.x;
    if (idx < 9 * COUT * CMID) {
        int ci  = idx % CMID;
        int t   = idx / CMID;
        int co  = t % COUT;
        int khw = t / COUT;
        wr[idx] = __float2bfloat16(w[(co * CMID + ci) * 9 + khw]);
    }
}

// ---------------------------------------------------------------
// Kernel B: bilinear shift + Maclaurin powers -> y NHWC bf16
// y layout: [n][h][w][c3], c3 = c + 64*(power-1), shape (16,112,112,192)
// ---------------------------------------------------------------
#define TSTRIDE 196   // 192 + 4 pad (98 dwords => stride 2 mod 32 banks)

__global__ __launch_bounds__(256) void shift_pow_kernel(
    const float* __restrict__ x, const float* __restrict__ shifts,
    __hip_bfloat16* __restrict__ y)
{
    __shared__ __hip_bfloat16 tile[W_DIM * TSTRIDE];

    const int n   = blockIdx.y;
    const int h   = blockIdx.x;
    const int tid = threadIdx.x;
    const int wl  = tid & 63;
    const int c0  = tid >> 6;   // 0..3

    for (int c = c0; c < CIN; c += 4) {
        float sx = shifts[2 * c]     * 4.0f;
        float sy = shifts[2 * c + 1] * 4.0f;
        float fx = floorf(sx), fy = floorf(sy);
        float wx = sx - fx,    wy = sy - fy;
        int   ix = (int)fx,    iy = (int)fy;

        int r0 = h + iy, r1 = r0 + 1;
        bool r0v = (unsigned)r0 < (unsigned)H_DIM;
        bool r1v = (unsigned)r1 < (unsigned)H_DIM;

        const float* xp  = x + ((size_t)(n * CIN + c) * H_DIM) * W_DIM;
        const float* xr0 = xp + r0 * W_DIM;
        const float* xr1 = xp + r1 * W_DIM;

        #pragma unroll
        for (int wb = 0; wb < 2; ++wb) {
            int px = wb * 64 + wl;
            if (px < W_DIM) {
                int cl0 = px + ix, cl1 = cl0 + 1;
                bool c0v = (unsigned)cl0 < (unsigned)W_DIM;
                bool c1v = (unsigned)cl1 < (unsigned)W_DIM;
                float t00 = (r0v && c0v) ? xr0[cl0] : 0.0f;
                float t01 = (r0v && c1v) ? xr0[cl1] : 0.0f;
                float t10 = (r1v && c0v) ? xr1[cl0] : 0.0f;
                float t11 = (r1v && c1v) ? xr1[cl1] : 0.0f;
                float v  = (1.0f - wy) * ((1.0f - wx) * t00 + wx * t01)
                         +         wy  * ((1.0f - wx) * t10 + wx * t11);
                float v2 = v * v;
                float v3 = v2 * v;
                __hip_bfloat16* tp = &tile[px * TSTRIDE];
                tp[c]       = __float2bfloat16(v);
                tp[c + 64]  = __float2bfloat16(v2);
                tp[c + 128] = __float2bfloat16(v3);
            }
        }
    }
    __syncthreads();

    // coalesced write-out: 112 px * 96 dwords = 10752 dwords, 42 iters * 256 thr
    const unsigned* tl = (const unsigned*)tile;
    unsigned* yo = (unsigned*)(y + ((size_t)(n * H_DIM + h) * W_DIM) * CMID);
    #pragma unroll 2
    for (int it = 0; it < 42; ++it) {
        int idx = it * 256 + tid;
        int px  = idx / 96;
        int cp  = idx - px * 96;
        yo[idx] = tl[px * 98 + cp];
    }
}

// ---------------------------------------------------------------
// Kernel C: implicit-GEMM 3x3 conv, bf16 MFMA 16x16x32, LDS-staged B.
// Block = 128 co x 112 px (one output row), 4 waves, wave = 32 co x 112 px.
// Per kh: stage y row (112x192 bf16, contiguous) into LDS with stride 200
// (bank-uniform for ds_read_b128), halo px slots pre-zeroed.
// A (weights [khw][co][192]) read direct from L2, 6 frags batched per chunk.
// ---------------------------------------------------------------
#define YSTRIDE 200   // 192 + 8 pad elements; 400B => bank group 4*(m+quad)%32, uniform

__global__ __launch_bounds__(256, 3) void conv_kernel(
    const __bf16* __restrict__ y,    // [16][112][112][192]
    const __bf16* __restrict__ wr,   // [9][128][192]
    const float* __restrict__ bias,
    float* __restrict__ out)         // [16][128][112][112]
{
    __shared__ __align__(16) __bf16 ybuf[114 * YSTRIDE];   // 45.6 KB

    const int tid  = threadIdx.x;
    const int lane = tid & 63;
    const int wid  = tid >> 6;     // 0..3 -> co block of 32
    const int m    = lane & 15;
    const int quad = lane >> 4;

    const int h = blockIdx.x;
    const int n = blockIdx.y;

    // zero the halo slots (px=-1 -> slot 0, px=112 -> slot 113), incl. pad
    {
        unsigned* zb = (unsigned*)ybuf;
        if (tid < 100) {
            zb[tid] = 0u;
            zb[113 * (YSTRIDE / 2) + tid] = 0u;
        }
    }

    f32x4 acc[2][7];
    #pragma unroll
    for (int mt = 0; mt < 2; ++mt)
        #pragma unroll
        for (int nt = 0; nt < 7; ++nt)
            #pragma unroll
            for (int r = 0; r < 4; ++r) acc[mt][nt][r] = 0.0f;

    const __bf16* ybase = y + (size_t)n * (H_DIM * W_DIM * CMID);

    for (int kh = 0; kh < 3; ++kh) {
        int row = h + kh - 1;
        if ((unsigned)row >= (unsigned)H_DIM) continue;   // uniform per block

        __syncthreads();   // ybuf free (prev kh compute done)

        // stage the full y row: 112*192 bf16 = 2688 x 16B, coalesced
        {
            const uint4* src = (const uint4*)(ybase + (size_t)row * (W_DIM * CMID));
            #pragma unroll
            for (int it = 0; it < 11; ++it) {
                int g = it * 256 + tid;
                if (g < 2688) {
                    int px   = g / 24;           // 24 x 16B per px
                    int part = g - px * 24;
                    *(uint4*)&ybuf[(px + 1) * YSTRIDE + part * 8] = src[g];
                }
            }
        }
        __syncthreads();

        for (int chunk = 0; chunk < 6; ++chunk) {
            const int kb = chunk * 32 + quad * 8;

            // batch-load 6 A fragments (2 co-subtiles x 3 kw) from L2
            bf16x8 af[3][2];
            #pragma unroll
            for (int kw = 0; kw < 3; ++kw)
                #pragma unroll
                for (int mt = 0; mt < 2; ++mt)
                    af[kw][mt] = *(const bf16x8*)(
                        wr + (size_t)((kh * 3 + kw) * COUT + wid * 32 + mt * 16 + m) * CMID + kb);

            #pragma unroll
            for (int kw = 0; kw < 3; ++kw) {
                #pragma unroll
                for (int nt = 0; nt < 7; ++nt) {
                    // B fragment: px = nt*16 + m + kw - 1 -> slot px+1
                    bf16x8 bfrag = *(const bf16x8*)&ybuf[(nt * 16 + m + kw) * YSTRIDE + kb];
                    acc[0][nt] = __builtin_amdgcn_mfma_f32_16x16x32_bf16(
                        af[kw][0], bfrag, acc[0][nt], 0, 0, 0);
                    acc[1][nt] = __builtin_amdgcn_mfma_f32_16x16x32_bf16(
                        af[kw][1], bfrag, acc[1][nt], 0, 0, 0);
                }
            }
        }
    }

    // epilogue: D col = px (lane&15), row = quad*4+r -> co
    #pragma unroll
    for (int mt = 0; mt < 2; ++mt) {
        const int co0 = wid * 32 + mt * 16 + quad * 4;
        float bv[4];
        #pragma unroll
        for (int r = 0; r < 4; ++r) bv[r] = bias[co0 + r];
        #pragma unroll
        for (int nt = 0; nt < 7; ++nt) {
            int j = nt * 16 + m;
            #pragma unroll
            for (int r = 0; r < 4; ++r) {
                out[(((size_t)n * COUT + co0 + r) * H_DIM + h) * W_DIM + j] =
                    acc[mt][nt][r] + bv[r];
            }
        }
    }
}

// ---------------------------------------------------------------
extern "C" void kernel_launch(void* const* d_in, const int* in_sizes, int n_in,
                              void* d_out, int out_size, void* d_ws, size_t ws_size,
                              hipStream_t stream) {
    const float* x      = (const float*)d_in[0];
    const float* w      = (const float*)d_in[1];
    const float* bias   = (const float*)d_in[2];
    const float* shifts = (const float*)d_in[3];
    float* out = (float*)d_out;

    __hip_bfloat16* y  = (__hip_bfloat16*)d_ws;                       // 77,070,336 B
    __hip_bfloat16* wr = (__hip_bfloat16*)((char*)d_ws + 77070336);   //    442,368 B

    repack_w_kernel<<<dim3((9 * COUT * CMID + 255) / 256), 256, 0, stream>>>(w, wr);
    shift_pow_kernel<<<dim3(H_DIM, NB), 256, 0, stream>>>(x, shifts, y);
    conv_kernel<<<dim3(H_DIM, NB), 256, 0, stream>>>(
        (const __bf16*)y, (const __bf16*)wr, bias, out);
}